// Round 12
// baseline (137.323 us; speedup 1.0000x reference)
//
#include <hip/hip_runtime.h>
#include <stdint.h>

#define KD 256
#define NO 256
#define NE 16
#define BM 64
#define BN 128
#define XROW 264        // X stage row stride (shorts): 256 + 8 pad
#define GROW 68         // gate_t row stride (floats)

typedef short bf16x8 __attribute__((ext_vector_type(8)));
typedef float f32x4 __attribute__((ext_vector_type(4)));

__device__ __forceinline__ unsigned short f2bf(float f) {
  uint32_t u = __float_as_uint(f);
  u += 0x7fffu + ((u >> 16) & 1u);   // RNE (finite inputs)
  return (unsigned short)(u >> 16);
}
__device__ __forceinline__ float bf2f(unsigned short h) {
  return __uint_as_float(((uint32_t)h) << 16);
}
// gelu(h) = h * sigmoid(h*(1.5957691 + 0.0713548 h^2))  (tanh form)
__device__ __forceinline__ float gelu_f(float h) {
#if __has_builtin(__builtin_amdgcn_exp2f)
  float zn = h * fmaf(-0.10294817f, h * h, -2.3022077f);   // -z*log2(e)
  return h * __builtin_amdgcn_rcpf(1.0f + __builtin_amdgcn_exp2f(zn));
#else
  float z = h * fmaf(0.07135481627f, h * h, 1.5957691216f);
  return h * __builtin_amdgcn_rcpf(1.0f + __expf(-z));
#endif
}

// async 16B global->LDS DMA (no VGPR round-trip; vmcnt-counted)
__device__ __forceinline__ void dma16(const void* g, void* l) {
  __builtin_amdgcn_global_load_lds(
      (const __attribute__((address_space(1))) uint32_t*)g,
      (__attribute__((address_space(3))) uint32_t*)l, 16, 0, 0);
}

// ---- prep: wave-parallel direct pack (R8, proven; 16x16 Wf layout).
// element We[e][kc*32+(lane>>4)*8+i][ob*16+(lane&15)] at
// Wf[(((e*8+kc)*16+ob)*64+lane)*8 + i].
__global__ void moe_prep(const float* __restrict__ We, unsigned short* __restrict__ Wf,
                         const float* __restrict__ Wg, unsigned short* __restrict__ Wgt)
{
  const int tid = threadIdx.x;
  const int bid = blockIdx.x;
  const int w = tid >> 6, lane = tid & 63;
  const int g = bid * 4 + w;                 // 2048 tasks = 16e x 8kc x 16ob
  const int e = g >> 7, kc = (g >> 4) & 7, ob = g & 15;
  const int q = lane >> 4, ln = lane & 15;

  const float* src = We + ((size_t)e * KD + kc * 32 + q * 8) * NO + ob * 16 + ln;
  unsigned int pk[4];
#pragma unroll
  for (int h = 0; h < 4; ++h) {
    unsigned short lo = f2bf(src[(h * 2 + 0) * NO]);
    unsigned short hi = f2bf(src[(h * 2 + 1) * NO]);
    pk[h] = (unsigned int)lo | ((unsigned int)hi << 16);
  }
  uint4* dst = (uint4*)(Wf + ((((size_t)(e * 8 + kc) * 16 + ob) * 64) + lane) * 8);
  *dst = make_uint4(pk[0], pk[1], pk[2], pk[3]);

  if (bid == 0) {   // Wgt: tiny (8 KB), block 0 tail
    int d = tid;
    const float* wr = Wg + (size_t)d * NE;
#pragma unroll
    for (int ee = 0; ee < NE; ++ee)
      Wgt[ee * KD + d] = f2bf(wr[ee]);
  }
}

// ---- main v12: B via async global_load_lds double-buffer (2 experts deep).
// Ledger (R0-R11): B-streaming cadence ~2 B/cyc/wave (reg-ring allows ~2
// loads in flight -> every kc-group pays L2 latency). Fix: per-wave-private
// LDS slab pair (16 KB each), 16 DMA/expert issued in one burst, 2 experts
// outstanding (~32 loads in flight), counted vmcnt(16) per expert (0 only at
// the tail). Consume = lane-linear ds_read_b128 (conflict-free). a[4][8],
// gate, epilogue, store are R0-byte-equal -> bit-identical output.
// LDS 136 KB -> 1 block/CU (1 wave/SIMD): hiding comes from DMA depth.
__launch_bounds__(256, 1)
__global__ void moe_main(const float* __restrict__ x,
                         const uint4* __restrict__ Wf,
                         const unsigned short* __restrict__ Wgt,
                         const float* __restrict__ be,
                         const float* __restrict__ bg,
                         float* __restrict__ out)
{
  __shared__ __align__(16) unsigned char BB[131072];   // B slabs; overlays Xs (dead after init)
  __shared__ __align__(16) float gate_t[NE * GROW];     // 4352 B
  __shared__ unsigned short be_h[NE * BN];              // 4096 B  (total 139520 B)

  unsigned short* const Xs = (unsigned short*)BB;       // [BM][XROW] staging view

  const int tid = threadIdx.x;
  const int bid = blockIdx.x;
  const int half = bid & 1;
  const int n0 = half * BN;
  const int m0 = (bid >> 1) * BM;
  const int w = tid >> 6, lane = tid & 63;   // wave w owns cols w*32..w*32+31 (disjoint B)
  const int ln = lane & 15, quad = lane >> 4;
  const int eoff = __builtin_amdgcn_readfirstlane(((tid >> 6) * 4 + bid) & 15);
  const int obb = half * 8 + w * 2;          // ob base for this wave (j adds +0/+1)

  // ---- stage X tile fp32 -> bf16
  {
    const float4* xg = (const float4*)x + (size_t)m0 * (KD / 4);
#pragma unroll
    for (int p = 0; p < 16; ++p) {
      int idx = p * 256 + tid;
      int r = idx >> 6, c = idx & 63;
      float4 v = xg[r * (KD / 4) + c];
      uint32_t lo = (uint32_t)f2bf(v.x) | ((uint32_t)f2bf(v.y) << 16);
      uint32_t hi = (uint32_t)f2bf(v.z) | ((uint32_t)f2bf(v.w) << 16);
      *(uint2*)&Xs[r * XROW + c * 4] = make_uint2(lo, hi);
    }
  }
  // ---- stage bias (bf16; |be|<=1/16 -> error ~1e-4)
#pragma unroll
  for (int p = 0; p < 8; ++p) {
    int idx = p * 256 + tid;
    int e = idx >> 7, c = idx & 127;
    be_h[e * BN + c] = f2bf(be[e * NO + n0 + c]);
  }
  __syncthreads();

  // ---- A fragments, FULL tile (64 rows x K=256): 32 frags, loaded ONCE
  bf16x8 a[4][8];
#pragma unroll
  for (int i = 0; i < 4; ++i)
#pragma unroll
    for (int kc = 0; kc < 8; ++kc)
      a[i][kc] = *(const bf16x8*)&Xs[(i * 16 + ln) * XROW + kc * 32 + quad * 8];

  // ---- gate: wave w computes rows w*16..w*16+15 for all 16 experts (lane ln = expert)
  {
    f32x4 g = {0.f, 0.f, 0.f, 0.f};
#pragma unroll
    for (int kc = 0; kc < 8; ++kc) {
      bf16x8 af = *(const bf16x8*)&Xs[(w * 16 + ln) * XROW + kc * 32 + quad * 8];
      bf16x8 wb = *(const bf16x8*)(Wgt + (size_t)ln * KD + kc * 32 + quad * 8);
      g = __builtin_amdgcn_mfma_f32_16x16x32_bf16(af, wb, g, 0, 0, 0);
    }
    float bgl = bg[ln];
#pragma unroll
    for (int r = 0; r < 4; ++r) {
      float v = g[r] + bgl;
      float mx = v;
#pragma unroll
      for (int msk = 1; msk < 16; msk <<= 1)
        mx = fmaxf(mx, __shfl_xor(mx, msk, 64));
      float ev = __expf(v - mx);
      float s = ev;
#pragma unroll
      for (int msk = 1; msk < 16; msk <<= 1)
        s += __shfl_xor(s, msk, 64);
      gate_t[ln * GROW + w * 16 + quad * 4 + r] = ev * __builtin_amdgcn_rcpf(s);
    }
  }
  __syncthreads();   // gate_t ready; all Xs reads done -> BB becomes B slabs

  // ---- per-wave DMA slabs + 2-expert-deep prologue
  const char* const WfB = (const char*)Wf;          // [e]131072 [kc]16384 [ob]1024 [lane]16
  char* const slab0 = (char*)BB + w * 32768;
  char* const slab1 = slab0 + 16384;
  {
    const char* s0 = WfB + (size_t)eoff * 131072 + (size_t)obb * 1024 + lane * 16;
    const char* s1 = WfB + (size_t)((eoff + 1) & 15) * 131072 + (size_t)obb * 1024 + lane * 16;
#pragma unroll
    for (int s = 0; s < 16; ++s)
      dma16(s0 + (s >> 1) * 16384 + (s & 1) * 1024, slab0 + s * 1024 + lane * 16);
#pragma unroll
    for (int s = 0; s < 16; ++s)
      dma16(s1 + (s >> 1) * 16384 + (s & 1) * 1024, slab1 + s * 1024 + lane * 16);
  }

  f32x4 acc[4][2], oacc[4][2];
#pragma unroll
  for (int i = 0; i < 4; ++i)
#pragma unroll
    for (int j = 0; j < 2; ++j) {
      acc[i][j] = (f32x4){0.f, 0.f, 0.f, 0.f};
      oacc[i][j] = (f32x4){0.f, 0.f, 0.f, 0.f};
    }

#pragma unroll 1
  for (int ei = 0; ei < NE; ++ei) {
    const int e = (eoff + ei) & 15;

    // counted wait: this expert's 16 DMAs done; next expert's 16 stay in flight
    if (ei < NE - 1) {
      asm volatile("s_waitcnt vmcnt(16)" ::: "memory");
    } else {
      asm volatile("s_waitcnt vmcnt(0)" ::: "memory");
    }
    __builtin_amdgcn_sched_barrier(0);

    char* const cur = (ei & 1) ? slab1 : slab0;
    // ---- consume: 8 kc-groups, 2 ds_read_b128 + 8 MFMAs each
#pragma unroll
    for (int kc = 0; kc < 8; ++kc) {
      const bf16x8 b0 = *(const bf16x8*)(cur + (kc * 2 + 0) * 1024 + lane * 16);
      const bf16x8 b1 = *(const bf16x8*)(cur + (kc * 2 + 1) * 1024 + lane * 16);
#pragma unroll
      for (int i = 0; i < 4; ++i) {
        acc[i][0] = __builtin_amdgcn_mfma_f32_16x16x32_bf16(a[i][kc], b0, acc[i][0], 0, 0, 0);
        acc[i][1] = __builtin_amdgcn_mfma_f32_16x16x32_bf16(a[i][kc], b1, acc[i][1], 0, 0, 0);
      }
    }

    // ---- refill this slab with expert ei+2 (issued before epilogue; the DMA
    // data returns >=300 cyc later, long after the ds_reads above completed)
    if (ei < NE - 2) {
      const int en2 = (eoff + ei + 2) & 15;
      const char* sn = WfB + (size_t)en2 * 131072 + (size_t)obb * 1024 + lane * 16;
#pragma unroll
      for (int s = 0; s < 16; ++s)
        dma16(sn + (s >> 1) * 16384 + (s & 1) * 1024, cur + s * 1024 + lane * 16);
    }

    // ---- expert epilogue: bias + gelu + gate-weighted accumulate (R0-exact)
    {
      f32x4 gv[4];
#pragma unroll
      for (int i = 0; i < 4; ++i)
        gv[i] = *(const f32x4*)&gate_t[e * GROW + i * 16 + quad * 4];
      const float bb0 = bf2f(be_h[e * BN + w * 32 + ln]);
      const float bb1 = bf2f(be_h[e * BN + w * 32 + 16 + ln]);
#pragma unroll
      for (int i = 0; i < 4; ++i)
#pragma unroll
        for (int j = 0; j < 2; ++j)
#pragma unroll
          for (int r = 0; r < 4; ++r) {
            float hh = acc[i][j][r] + (j ? bb1 : bb0);
            oacc[i][j][r] = fmaf(gv[i][r], gelu_f(hh), oacc[i][j][r]);
            acc[i][j][r] = 0.f;
          }
    }
  }

  // ---- store (each out element owned by exactly one wave)
#pragma unroll
  for (int i = 0; i < 4; ++i)
#pragma unroll
    for (int r = 0; r < 4; ++r) {
      int row = m0 + i * 16 + quad * 4 + r;
      float* orow = out + (size_t)row * NO + n0 + w * 32 + ln;
      orow[0]  = oacc[i][0][r];
      orow[16] = oacc[i][1][r];
    }
}

extern "C" void kernel_launch(void* const* d_in, const int* in_sizes, int n_in,
                              void* d_out, int out_size, void* d_ws, size_t ws_size,
                              hipStream_t stream) {
  const float* x  = (const float*)d_in[0];
  const float* We = (const float*)d_in[1];
  const float* be = (const float*)d_in[2];
  const float* Wg = (const float*)d_in[3];
  const float* bg = (const float*)d_in[4];
  float* out = (float*)d_out;
  unsigned short* Wf  = (unsigned short*)d_ws;                                      // 2 MB bf16, fragment-ordered
  unsigned short* Wgt = (unsigned short*)((char*)d_ws + (size_t)NE * NO * KD * 2);  // 8 KB bf16 [E][D]

  moe_prep<<<512, 256, 0, stream>>>(We, Wf, Wg, Wgt);
  moe_main<<<512, 256, 0, stream>>>(x, (const uint4*)Wf, Wgt, be, bg, out);
}

// Round 13
// 127.506 us; speedup vs baseline: 1.0770x; 1.0770x over previous
//
#include <hip/hip_runtime.h>
#include <stdint.h>

#define KD 256
#define NO 256
#define NE 16
#define BM 128          // rows per block (4 waves x 32 rows)
#define BN 64           // cols per block (shared B stream)
#define XROW 264        // X stage row stride (shorts): 256 + 8 pad
#define GROW 132        // gate_t row stride (floats); 128 rows used

typedef short bf16x8 __attribute__((ext_vector_type(8)));
typedef float f32x4 __attribute__((ext_vector_type(4)));

__device__ __forceinline__ unsigned short f2bf(float f) {
  uint32_t u = __float_as_uint(f);
  u += 0x7fffu + ((u >> 16) & 1u);   // RNE (finite inputs)
  return (unsigned short)(u >> 16);
}
__device__ __forceinline__ float bf2f(unsigned short h) {
  return __uint_as_float(((uint32_t)h) << 16);
}
// gelu(h) = h * sigmoid(h*(1.5957691 + 0.0713548 h^2))  (tanh form)
__device__ __forceinline__ float gelu_f(float h) {
#if __has_builtin(__builtin_amdgcn_exp2f)
  float zn = h * fmaf(-0.10294817f, h * h, -2.3022077f);   // -z*log2(e)
  return h * __builtin_amdgcn_rcpf(1.0f + __builtin_amdgcn_exp2f(zn));
#else
  float z = h * fmaf(0.07135481627f, h * h, 1.5957691216f);
  return h * __builtin_amdgcn_rcpf(1.0f + __expf(-z));
#endif
}

// async 16B global->LDS DMA (no VGPR round-trip; vmcnt-counted). R12-proven.
__device__ __forceinline__ void dma16(const void* g, void* l) {
  __builtin_amdgcn_global_load_lds(
      (const __attribute__((address_space(1))) uint32_t*)g,
      (__attribute__((address_space(3))) uint32_t*)l, 16, 0, 0);
}

// ---- prep: wave-parallel direct pack (R8, proven; 16x16 Wf layout).
// element We[e][kc*32+(lane>>4)*8+i][ob*16+(lane&15)] at
// Wf[(((e*8+kc)*16+ob)*64+lane)*8 + i].
__global__ void moe_prep(const float* __restrict__ We, unsigned short* __restrict__ Wf,
                         const float* __restrict__ Wg, unsigned short* __restrict__ Wgt)
{
  const int tid = threadIdx.x;
  const int bid = blockIdx.x;
  const int w = tid >> 6, lane = tid & 63;
  const int g = bid * 4 + w;                 // 2048 tasks = 16e x 8kc x 16ob
  const int e = g >> 7, kc = (g >> 4) & 7, ob = g & 15;
  const int q = lane >> 4, ln = lane & 15;

  const float* src = We + ((size_t)e * KD + kc * 32 + q * 8) * NO + ob * 16 + ln;
  unsigned int pk[4];
#pragma unroll
  for (int h = 0; h < 4; ++h) {
    unsigned short lo = f2bf(src[(h * 2 + 0) * NO]);
    unsigned short hi = f2bf(src[(h * 2 + 1) * NO]);
    pk[h] = (unsigned int)lo | ((unsigned int)hi << 16);
  }
  uint4* dst = (uint4*)(Wf + ((((size_t)(e * 8 + kc) * 16 + ob) * 64) + lane) * 8);
  *dst = make_uint4(pk[0], pk[1], pk[2], pk[3]);

  if (bid == 0) {   // Wgt: tiny (8 KB), block 0 tail
    int d = tid;
    const float* wr = Wg + (size_t)d * NE;
#pragma unroll
    for (int ee = 0; ee < NE; ++ee)
      Wgt[ee * KD + d] = f2bf(wr[ee]);
  }
}

// ---- main v13: shared-B tall tile (128x64), DMA double-buffer, TLP intact.
// Ledger: per-CU B-ingest (2 MB @ ~15 B/cyc/CU) is the only quantity
// correlated with the invariant 55.5 us (R5: 2x traffic -> +21%; everything
// else neutral). This halves it: 4 waves share one 32 KB/expert B slab,
// DMA'd 2 experts deep with counted vmcnt(8) + RAW s_barrier (no vmcnt(0)
// drain). All 4 waves do identical work between barriers; the 2 blocks/CU
// stay mutually async (anti-phase preserved). Per-output math chain is
// R0-identical -> bit-identical results (absmax gate = race detector).
__launch_bounds__(256, 2)
__global__ void moe_main(const float* __restrict__ x,
                         const uint4* __restrict__ Wf,
                         const unsigned short* __restrict__ Wgt,
                         const float* __restrict__ be,
                         const float* __restrict__ bg,
                         float* __restrict__ out)
{
  __shared__ __align__(16) unsigned char BB[BM * XROW * 2];  // 67584 B: Xs stage, then 2x32KB B slabs
  __shared__ __align__(16) float gate_t[NE * GROW];           // 8448 B
  __shared__ unsigned short be_h[NE * BN];                    // 2048 B  (total 78080 B -> 2 blocks/CU)

  const int tid = threadIdx.x;
  const int bid = blockIdx.x;
  const int cq = bid & 3;                    // col quarter
  const int n0 = cq * BN;
  const int m0 = (bid >> 2) * BM;
  const int w = tid >> 6, lane = tid & 63;   // wave w owns rows w*32..w*32+31, ALL 64 cols
  const int ln = lane & 15, quad = lane >> 4;
  // BLOCK-uniform expert rotation (all 4 waves share the B slab)
  const int eoff = __builtin_amdgcn_readfirstlane(bid & 15);
  const int obBase = cq * 4;                 // first 16-col frag index of this block

  unsigned short* const Xs = (unsigned short*)BB;

  // ---- stage X tile fp32 -> bf16 (128 rows)
  {
    const float4* xg = (const float4*)x + (size_t)m0 * (KD / 4);
#pragma unroll
    for (int p = 0; p < 32; ++p) {
      int idx = p * 256 + tid;
      int r = idx >> 6, c = idx & 63;
      float4 v = xg[r * (KD / 4) + c];
      uint32_t lo = (uint32_t)f2bf(v.x) | ((uint32_t)f2bf(v.y) << 16);
      uint32_t hi = (uint32_t)f2bf(v.z) | ((uint32_t)f2bf(v.w) << 16);
      *(uint2*)&Xs[r * XROW + c * 4] = make_uint2(lo, hi);
    }
  }
  // ---- stage bias (bf16; |be|<=1/16 -> error ~1e-4)
#pragma unroll
  for (int p = 0; p < 4; ++p) {
    int idx = p * 256 + tid;
    int e = idx >> 6, c = idx & 63;
    be_h[e * BN + c] = f2bf(be[e * NO + n0 + c]);
  }
  __syncthreads();

  // ---- A fragments: rows w*32..+31, full K. 16 frags = 64 regs.
  bf16x8 a[2][8];
#pragma unroll
  for (int i = 0; i < 2; ++i)
#pragma unroll
    for (int kc = 0; kc < 8; ++kc)
      a[i][kc] = *(const bf16x8*)&Xs[(w * 32 + i * 16 + ln) * XROW + kc * 32 + quad * 8];

  // ---- gate: 128 rows = 8 groups; wave w does groups 2w, 2w+1 (lane ln = expert)
#pragma unroll
  for (int pass = 0; pass < 2; ++pass) {
    const int rw = w * 2 + pass;
    f32x4 g = {0.f, 0.f, 0.f, 0.f};
#pragma unroll
    for (int kc = 0; kc < 8; ++kc) {
      bf16x8 af = *(const bf16x8*)&Xs[(rw * 16 + ln) * XROW + kc * 32 + quad * 8];
      bf16x8 wb = *(const bf16x8*)(Wgt + (size_t)ln * KD + kc * 32 + quad * 8);
      g = __builtin_amdgcn_mfma_f32_16x16x32_bf16(af, wb, g, 0, 0, 0);
    }
    float bgl = bg[ln];
#pragma unroll
    for (int r = 0; r < 4; ++r) {
      float v = g[r] + bgl;
      float mx = v;
#pragma unroll
      for (int msk = 1; msk < 16; msk <<= 1)
        mx = fmaxf(mx, __shfl_xor(mx, msk, 64));
      float ev = __expf(v - mx);
      float s = ev;
#pragma unroll
      for (int msk = 1; msk < 16; msk <<= 1)
        s += __shfl_xor(s, msk, 64);
      gate_t[ln * GROW + rw * 16 + quad * 4 + r] = ev * __builtin_amdgcn_rcpf(s);
    }
  }
  __syncthreads();   // gate done; ALL Xs reads complete -> BB becomes B slabs

  // ---- B slabs + 2-expert-deep DMA prologue.
  // Slab layout: [(kc*4+jf)*1024 + lane*16] = Wf frag (e, kc, obBase+jf).
  // Wave w fills kc in {2w, 2w+1} x jf 0..3 = 8 DMAs/expert.
  char* const slab0 = (char*)BB;
  char* const slab1 = (char*)BB + 32768;
  const char* const WfB = (const char*)Wf;
  {
    const int e1 = (eoff + 1) & 15;
#pragma unroll
    for (int s = 0; s < 8; ++s) {
      const int kc = w * 2 + (s >> 2), jf = s & 3;
      dma16(WfB + ((size_t)((eoff * 8 + kc) * 16 + obBase + jf)) * 1024 + lane * 16,
            slab0 + (kc * 4 + jf) * 1024 + lane * 16);
    }
#pragma unroll
    for (int s = 0; s < 8; ++s) {
      const int kc = w * 2 + (s >> 2), jf = s & 3;
      dma16(WfB + ((size_t)((e1 * 8 + kc) * 16 + obBase + jf)) * 1024 + lane * 16,
            slab1 + (kc * 4 + jf) * 1024 + lane * 16);
    }
  }

  f32x4 acc[2][4], oacc[2][4];
#pragma unroll
  for (int i = 0; i < 2; ++i)
#pragma unroll
    for (int jf = 0; jf < 4; ++jf) {
      acc[i][jf] = (f32x4){0.f, 0.f, 0.f, 0.f};
      oacc[i][jf] = (f32x4){0.f, 0.f, 0.f, 0.f};
    }

#pragma unroll 1
  for (int ei = 0; ei < NE; ++ei) {
    const int e = (eoff + ei) & 15;
    char* const cur = (ei & 1) ? slab1 : slab0;

    // counted wait (my 8 DMAs for cur done; next expert's 8 stay in flight),
    // then RAW barrier (join all waves) — no vmcnt(0) drain.
    if (ei < NE - 1) {
      asm volatile("s_waitcnt vmcnt(8)" ::: "memory");
    } else {
      asm volatile("s_waitcnt vmcnt(0)" ::: "memory");
    }
    __builtin_amdgcn_sched_barrier(0);
    __builtin_amdgcn_s_barrier();
    __builtin_amdgcn_sched_barrier(0);

    // ---- consume: ping-pong 4-frag groups; 8 MFMAs per kc
    bf16x8 bq0[4], bq1[4];
#pragma unroll
    for (int jf = 0; jf < 4; ++jf)
      bq0[jf] = *(const bf16x8*)(cur + jf * 1024 + lane * 16);
#pragma unroll
    for (int kc = 0; kc < 8; ++kc) {
      const bf16x8* cu = (kc & 1) ? bq1 : bq0;
      bf16x8* nx = (kc & 1) ? bq0 : bq1;
      if (kc < 7) {
#pragma unroll
        for (int jf = 0; jf < 4; ++jf)
          nx[jf] = *(const bf16x8*)(cur + ((kc + 1) * 4 + jf) * 1024 + lane * 16);
      }
#pragma unroll
      for (int i = 0; i < 2; ++i)
#pragma unroll
        for (int jf = 0; jf < 4; ++jf)
          acc[i][jf] = __builtin_amdgcn_mfma_f32_16x16x32_bf16(
              a[i][kc], cu[jf], acc[i][jf], 0, 0, 0);
    }

    // all waves finished reading cur -> safe to refill it
    __builtin_amdgcn_sched_barrier(0);
    __builtin_amdgcn_s_barrier();
    __builtin_amdgcn_sched_barrier(0);

    if (ei < NE - 2) {
      const int en2 = (eoff + ei + 2) & 15;
#pragma unroll
      for (int s = 0; s < 8; ++s) {
        const int kc = w * 2 + (s >> 2), jf = s & 3;
        dma16(WfB + ((size_t)((en2 * 8 + kc) * 16 + obBase + jf)) * 1024 + lane * 16,
              cur + (kc * 4 + jf) * 1024 + lane * 16);
      }
    }

    // ---- expert epilogue (R0-exact chain): bias + gelu + gate accumulate.
    // DMA flight time is covered by this epilogue + the next expert's MFMAs.
    {
      float bbf[4];
#pragma unroll
      for (int jf = 0; jf < 4; ++jf)
        bbf[jf] = bf2f(be_h[e * BN + jf * 16 + ln]);
#pragma unroll
      for (int i = 0; i < 2; ++i) {
        const f32x4 gq = *(const f32x4*)&gate_t[e * GROW + w * 32 + i * 16 + quad * 4];
#pragma unroll
        for (int jf = 0; jf < 4; ++jf)
#pragma unroll
          for (int r = 0; r < 4; ++r) {
            float hh = acc[i][jf][r] + bbf[jf];
            oacc[i][jf][r] = fmaf(gq[r], gelu_f(hh), oacc[i][jf][r]);
            acc[i][jf][r] = 0.f;
          }
      }
    }
  }

  // ---- store (each out element owned by exactly one wave)
#pragma unroll
  for (int i = 0; i < 2; ++i)
#pragma unroll
    for (int r = 0; r < 4; ++r) {
      int row = m0 + w * 32 + i * 16 + quad * 4 + r;
      float* orow = out + (size_t)row * NO + n0 + ln;
      orow[0]  = oacc[i][0][r];
      orow[16] = oacc[i][1][r];
      orow[32] = oacc[i][2][r];
      orow[48] = oacc[i][3][r];
    }
}

extern "C" void kernel_launch(void* const* d_in, const int* in_sizes, int n_in,
                              void* d_out, int out_size, void* d_ws, size_t ws_size,
                              hipStream_t stream) {
  const float* x  = (const float*)d_in[0];
  const float* We = (const float*)d_in[1];
  const float* be = (const float*)d_in[2];
  const float* Wg = (const float*)d_in[3];
  const float* bg = (const float*)d_in[4];
  float* out = (float*)d_out;
  unsigned short* Wf  = (unsigned short*)d_ws;                                      // 2 MB bf16, fragment-ordered
  unsigned short* Wgt = (unsigned short*)((char*)d_ws + (size_t)NE * NO * KD * 2);  // 8 KB bf16 [E][D]

  moe_prep<<<512, 256, 0, stream>>>(We, Wf, Wg, Wgt);
  moe_main<<<512, 256, 0, stream>>>(x, (const uint4*)Wf, Wgt, be, bg, out);
}

// Round 14
// 121.114 us; speedup vs baseline: 1.1338x; 1.0528x over previous
//
#include <hip/hip_runtime.h>
#include <stdint.h>

#define KD 256
#define NO 256
#define NE 16
#define BM 64
#define BN 128
#define XROW 264        // X stage row stride (shorts): 256 + 8 pad
#define GROW 68         // gate_t row stride (floats)

typedef short bf16x8 __attribute__((ext_vector_type(8)));
typedef float f32x4 __attribute__((ext_vector_type(4)));
typedef float f32x2 __attribute__((ext_vector_type(2)));

__device__ __forceinline__ unsigned short f2bf(float f) {
  uint32_t u = __float_as_uint(f);
  u += 0x7fffu + ((u >> 16) & 1u);   // RNE (finite inputs)
  return (unsigned short)(u >> 16);
}
__device__ __forceinline__ float bf2f(unsigned short h) {
  return __uint_as_float(((uint32_t)h) << 16);
}
// gelu*gate accumulate on f32x2 so the backend emits v_pk_{mul,add,fma}_f32.
// Value-identical chain to R0's scalar gelu_f (same constants, same op order;
// verified: R1 and R11 both passed with absmax unchanged using this path).
__device__ __forceinline__ void epi_pair(f32x2 h, f32x2 gv, f32x2& o) {
  f32x2 t = h * h;
  f32x2 s = __builtin_elementwise_fma(t, (f32x2){-0.10294817f, -0.10294817f},
                                      (f32x2){-2.3022077f, -2.3022077f});
  f32x2 zn = h * s;
  f32x2 ev;
  ev.x = __builtin_amdgcn_exp2f(zn.x);
  ev.y = __builtin_amdgcn_exp2f(zn.y);
  f32x2 den = ev + 1.0f;
  f32x2 r;
  r.x = __builtin_amdgcn_rcpf(den.x);
  r.y = __builtin_amdgcn_rcpf(den.y);
  f32x2 g = h * r;
  o = __builtin_elementwise_fma(gv, g, o);
}

// ---- prep: wave-parallel direct pack (R8, proven). Wf layout unchanged:
// element We[e][kc*32+(lane>>4)*8+i][ob*16+(lane&15)] at
// Wf[(((e*8+kc)*16+ob)*64+lane)*8 + i].
__global__ void moe_prep(const float* __restrict__ We, unsigned short* __restrict__ Wf,
                         const float* __restrict__ Wg, unsigned short* __restrict__ Wgt)
{
  const int tid = threadIdx.x;
  const int bid = blockIdx.x;
  const int w = tid >> 6, lane = tid & 63;
  const int g = bid * 4 + w;                 // 2048 tasks = 16e x 8kc x 16ob
  const int e = g >> 7, kc = (g >> 4) & 7, ob = g & 15;
  const int q = lane >> 4, ln = lane & 15;

  const float* src = We + ((size_t)e * KD + kc * 32 + q * 8) * NO + ob * 16 + ln;
  unsigned int pk[4];
#pragma unroll
  for (int h = 0; h < 4; ++h) {
    unsigned short lo = f2bf(src[(h * 2 + 0) * NO]);
    unsigned short hi = f2bf(src[(h * 2 + 1) * NO]);
    pk[h] = (unsigned int)lo | ((unsigned int)hi << 16);
  }
  uint4* dst = (uint4*)(Wf + ((((size_t)(e * 8 + kc) * 16 + ob) * 64) + lane) * 8);
  *dst = make_uint4(pk[0], pk[1], pk[2], pk[3]);

  if (bid == 0) {   // Wgt: tiny (8 KB), block 0 tail
    int d = tid;
    const float* wr = Wg + (size_t)d * NE;
#pragma unroll
    for (int ee = 0; ee < NE; ++ee)
      Wgt[ee * KD + d] = f2bf(wr[ee]);
  }
}

// ---- main v14: EXACT R0 structure (proven best: 55.4 us, no spill) with ONE
// change: the per-expert epilogue runs on f32x2 pairs (v_pk_fma/mul) via
// epi_pair — halving the non-trans epilogue VALU issue slots. Single-variable
// test of the issue-budget model; numerics proven identical (R1/R11 absmax).
__launch_bounds__(256, 2)
__global__ void moe_main(const float* __restrict__ x,
                         const uint4* __restrict__ Wf,
                         const unsigned short* __restrict__ Wgt,
                         const float* __restrict__ be,
                         const float* __restrict__ bg,
                         float* __restrict__ out)
{
  __shared__ __align__(16) unsigned short Xs[BM * XROW];  // 33792 B
  __shared__ __align__(16) float gate_t[NE * GROW];        // 4352 B
  __shared__ unsigned short be_h[NE * BN];                 // 4096 B

  const int tid = threadIdx.x;
  const int bid = blockIdx.x;
  const int half = bid & 1;
  const int n0 = half * BN;
  const int m0 = (bid >> 1) * BM;
  const int w = tid >> 6, lane = tid & 63;   // wave w owns cols w*32..w*32+31 (disjoint B)
  const int ln = lane & 15, quad = lane >> 4;
  // per-wave expert rotation, scalarized so refill addresses stay SGPR-based
  const int eoff = __builtin_amdgcn_readfirstlane(((tid >> 6) * 4 + bid) & 15);

  // per-wave fragment offset (uint4 units); frag j at +j*64 (=1024 B imm)
  const int voff = (half * 8 + w * 2) * 64 + lane;

  // ---- stage X tile fp32 -> bf16
  {
    const float4* xg = (const float4*)x + (size_t)m0 * (KD / 4);
#pragma unroll
    for (int p = 0; p < 16; ++p) {
      int idx = p * 256 + tid;
      int r = idx >> 6, c = idx & 63;
      float4 v = xg[r * (KD / 4) + c];
      uint32_t lo = (uint32_t)f2bf(v.x) | ((uint32_t)f2bf(v.y) << 16);
      uint32_t hi = (uint32_t)f2bf(v.z) | ((uint32_t)f2bf(v.w) << 16);
      *(uint2*)&Xs[r * XROW + c * 4] = make_uint2(lo, hi);
    }
  }
  // ---- ring fill: sets 0..3 of rotated sequence = expert eoff, kc 0..3
  uint4 b[4][2];
#pragma unroll
  for (int kc = 0; kc < 4; ++kc) {
    const uint4* p = Wf + ((size_t)eoff * 8 + kc) * 1024 + voff;
    b[kc][0] = p[0]; b[kc][1] = p[64];
  }
  // ---- stage bias (bf16; |be|<=1/16 -> error ~1e-4)
#pragma unroll
  for (int p = 0; p < 8; ++p) {
    int idx = p * 256 + tid;
    int e = idx >> 7, c = idx & 127;
    be_h[e * BN + c] = f2bf(be[e * NO + n0 + c]);
  }
  __syncthreads();

  // ---- A fragments, FULL tile (64 rows x K=256): 32 frags, loaded ONCE (live in AGPRs)
  bf16x8 a[4][8];
#pragma unroll
  for (int i = 0; i < 4; ++i)
#pragma unroll
    for (int kc = 0; kc < 8; ++kc)
      a[i][kc] = *(const bf16x8*)&Xs[(i * 16 + ln) * XROW + kc * 32 + quad * 8];

  // ---- gate: wave w computes rows w*16..w*16+15 for all 16 experts (lane ln = expert)
  {
    f32x4 g = {0.f, 0.f, 0.f, 0.f};
#pragma unroll
    for (int kc = 0; kc < 8; ++kc) {
      bf16x8 af = *(const bf16x8*)&Xs[(w * 16 + ln) * XROW + kc * 32 + quad * 8];
      bf16x8 wb = *(const bf16x8*)(Wgt + (size_t)ln * KD + kc * 32 + quad * 8);
      g = __builtin_amdgcn_mfma_f32_16x16x32_bf16(af, wb, g, 0, 0, 0);
    }
    float bgl = bg[ln];
#pragma unroll
    for (int r = 0; r < 4; ++r) {
      float v = g[r] + bgl;
      float mx = v;
#pragma unroll
      for (int msk = 1; msk < 16; msk <<= 1)
        mx = fmaxf(mx, __shfl_xor(mx, msk, 64));
      float ev = __expf(v - mx);
      float s = ev;
#pragma unroll
      for (int msk = 1; msk < 16; msk <<= 1)
        s += __shfl_xor(s, msk, 64);
      gate_t[ln * GROW + w * 16 + quad * 4 + r] = ev * __builtin_amdgcn_rcpf(s);
    }
  }
  __syncthreads();  // gate_t visible; last barrier in the kernel

  f32x4 acc[4][2], oacc[4][2];
#pragma unroll
  for (int i = 0; i < 4; ++i)
#pragma unroll
    for (int j = 0; j < 2; ++j) {
      acc[i][j] = (f32x4){0.f, 0.f, 0.f, 0.f};
      oacc[i][j] = (f32x4){0.f, 0.f, 0.f, 0.f};
    }

#pragma unroll 1
  for (int ei = 0; ei < NE; ++ei) {
    const int e  = (eoff + ei) & 15;        // this wave's current expert (scalar)
    const int en = (eoff + ei + 1) & 15;    // next expert (scalar)
    const uint4* bse = Wf + (size_t)e  * 8192 + voff;
    const uint4* bsn = Wf + (size_t)en * 8192 + voff;

#pragma unroll
    for (int kc = 0; kc < 8; ++kc) {
      uint4* bc = b[kc & 3];
#pragma unroll
      for (int i = 0; i < 4; ++i)
#pragma unroll
        for (int j = 0; j < 2; ++j)
          acc[i][j] = __builtin_amdgcn_mfma_f32_16x16x32_bf16(
              a[i][kc], *(const bf16x8*)&bc[j], acc[i][j], 0, 0, 0);
      // refill the slot just consumed with set 4 ahead
      if (kc < 4) {
        const uint4* p = bse + (kc + 4) * 1024;
        bc[0] = p[0]; bc[1] = p[64];
      } else if (ei < NE - 1) {
        const uint4* p = bsn + (kc - 4) * 1024;
        bc[0] = p[0]; bc[1] = p[64];
      }
    }
    // ---- expert epilogue: bias + gelu + gate accumulate (packed f32 pairs)
    {
      f32x4 gv[4];
#pragma unroll
      for (int i = 0; i < 4; ++i)
        gv[i] = *(const f32x4*)&gate_t[e * GROW + i * 16 + quad * 4];
      const float bb0 = bf2f(be_h[e * BN + w * 32 + ln]);
      const float bb1 = bf2f(be_h[e * BN + w * 32 + 16 + ln]);
#pragma unroll
      for (int i = 0; i < 4; ++i)
#pragma unroll
        for (int j = 0; j < 2; ++j) {
          const float bb = j ? bb1 : bb0;
          const f32x2 bb2 = {bb, bb};
          f32x2 h0 = {acc[i][j][0], acc[i][j][1]};
          f32x2 h1 = {acc[i][j][2], acc[i][j][3]};
          h0 = h0 + bb2;
          h1 = h1 + bb2;
          f32x2 o0 = {oacc[i][j][0], oacc[i][j][1]};
          f32x2 o1 = {oacc[i][j][2], oacc[i][j][3]};
          epi_pair(h0, (f32x2){gv[i][0], gv[i][1]}, o0);
          epi_pair(h1, (f32x2){gv[i][2], gv[i][3]}, o1);
          oacc[i][j][0] = o0.x; oacc[i][j][1] = o0.y;
          oacc[i][j][2] = o1.x; oacc[i][j][3] = o1.y;
          acc[i][j] = (f32x4){0.f, 0.f, 0.f, 0.f};
        }
    }
  }

  // ---- store (each out element owned by exactly one wave)
#pragma unroll
  for (int i = 0; i < 4; ++i)
#pragma unroll
    for (int r = 0; r < 4; ++r) {
      int row = m0 + i * 16 + quad * 4 + r;
      float* orow = out + (size_t)row * NO + n0 + w * 32 + ln;
      orow[0]  = oacc[i][0][r];
      orow[16] = oacc[i][1][r];
    }
}

extern "C" void kernel_launch(void* const* d_in, const int* in_sizes, int n_in,
                              void* d_out, int out_size, void* d_ws, size_t ws_size,
                              hipStream_t stream) {
  const float* x  = (const float*)d_in[0];
  const float* We = (const float*)d_in[1];
  const float* be = (const float*)d_in[2];
  const float* Wg = (const float*)d_in[3];
  const float* bg = (const float*)d_in[4];
  float* out = (float*)d_out;
  unsigned short* Wf  = (unsigned short*)d_ws;                                      // 2 MB bf16, fragment-ordered
  unsigned short* Wgt = (unsigned short*)((char*)d_ws + (size_t)NE * NO * KD * 2);  // 8 KB bf16 [E][D]

  moe_prep<<<512, 256, 0, stream>>>(We, Wf, Wg, Wgt);
  moe_main<<<512, 256, 0, stream>>>(x, (const uint4*)Wf, Wgt, be, bg, out);
}